// Round 1
// baseline (26764.441 us; speedup 1.0000x reference)
//
#include <hip/hip_runtime.h>
#include <hip/hip_bf16.h>
#include <math.h>

#define T_STEPS 512
#define B_SZ 256
#define I_SZ 256
#define H_SZ 1024

typedef unsigned short u16;
typedef __bf16 bf16x8 __attribute__((ext_vector_type(8)));
typedef float f32x4 __attribute__((ext_vector_type(4)));

__device__ __forceinline__ u16 f2bf(float f) {
    union { float f; unsigned u; } v; v.f = f;
    unsigned r = v.u + 0x7fffu + ((v.u >> 16) & 1u);  // RNE
    return (u16)(r >> 16);
}

// ---------------------------------------------------------------------------
// prep: fp32 -> bf16 conversions of weights + h0, zero team barrier counters.
// ws layout: [0,2MB) W_hh bf16 | [2MB,2.5MB) W_ih bf16 | hp0 512KB | hp1 512KB | ctr
// ---------------------------------------------------------------------------
__global__ void prep_kernel(const float* __restrict__ wih, const float* __restrict__ whh,
                            const float* __restrict__ h0,
                            u16* __restrict__ whh_b, u16* __restrict__ wih_b,
                            u16* __restrict__ hp0, unsigned* __restrict__ ctr) {
    int idx = blockIdx.x * blockDim.x + threadIdx.x;
    int stride = gridDim.x * blockDim.x;
    for (int i = idx; i < H_SZ * H_SZ; i += stride) whh_b[i] = f2bf(whh[i]);
    for (int i = idx; i < H_SZ * I_SZ; i += stride) wih_b[i] = f2bf(wih[i]);
    for (int i = idx; i < B_SZ * H_SZ; i += stride) hp0[i] = f2bf(h0[i]);
    if (idx < 8) ctr[idx] = 0;
}

// ---------------------------------------------------------------------------
// Persistent RNN kernel.
// Grid: 256 blocks x 256 threads (4 waves). 8 teams of 32 blocks:
//   team = blockIdx%8 -> batch rows [32*team, 32*team+32)
//   slice = blockIdx/8 -> hidden cols [32*slice, 32*slice+32)
// Wave quadrant inside the 32x32 tile: rows 16*(wid&1), cols 16*(wid>>1).
// W_hh slice (16 cols x 1024 K) and W_ih slice (16 cols x 256 K) pinned in
// registers as MFMA B-fragments (gemm_bt layout: W[n][k] row-major, lane
// reads 8 contiguous k at row n=lane&15, k-base quad*8).
// Per step: acc = x_t@W_ih^T (pre-barrier) + h_t@W_hh^T; tanh; EMA;
// publish bf16 h to double-buffered ws; signal team counter; write fp32 out.
// ---------------------------------------------------------------------------
__global__ void __launch_bounds__(256, 1)
rnn_persistent(const float* __restrict__ x, const float* __restrict__ h0,
               const float* __restrict__ bias,
               const u16* __restrict__ whh_b, const u16* __restrict__ wih_b,
               u16* __restrict__ hp0, u16* __restrict__ hp1,
               unsigned* __restrict__ ctr, float* __restrict__ out)
{
    const int tid  = threadIdx.x;
    const int wid  = tid >> 6;
    const int lane = tid & 63;
    const int l16  = lane & 15;
    const int quad = lane >> 4;

    const int team  = blockIdx.x & 7;
    const int slice = blockIdx.x >> 3;

    const int row_base = team * 32 + (wid & 1) * 16;       // wave's 16 batch rows
    const int gcol     = slice * 32 + (wid >> 1) * 16 + l16; // lane's hidden col (B n-idx & C col)
    const int am       = row_base + l16;                   // lane's A-frag row (m-idx)
    const int kq       = quad * 8;                         // lane's k base within a k-step

    // Pin W_hh / W_ih B-fragments in registers (persistent across all 512 steps)
    bf16x8 wB[32];
#pragma unroll
    for (int kk = 0; kk < 32; ++kk)
        wB[kk] = *reinterpret_cast<const bf16x8*>(whh_b + gcol * H_SZ + kk * 32 + kq);
    bf16x8 wI[8];
#pragma unroll
    for (int kx = 0; kx < 8; ++kx)
        wI[kx] = *reinterpret_cast<const bf16x8*>(wih_b + gcol * I_SZ + kx * 32 + kq);

    const float bias_v = bias[gcol];

    // fp32 master copy of this lane's 4 h elements (C-layout: row=quad*4+i, col=l16)
    float hown[4];
#pragma unroll
    for (int i = 0; i < 4; ++i)
        hown[i] = h0[(row_base + quad * 4 + i) * H_SZ + gcol];

    unsigned* my_ctr = ctr + team;

    for (int t = 0; t < T_STEPS; ++t) {
        const u16* hcur = (t & 1) ? hp1 : hp0;
        u16*       hnxt = (t & 1) ? hp0 : hp1;

        f32x4 acc0 = {0.f,0.f,0.f,0.f}, acc1 = {0.f,0.f,0.f,0.f};
        f32x4 acc2 = {0.f,0.f,0.f,0.f}, acc3 = {0.f,0.f,0.f,0.f};

        // ---- x_t @ W_ih^T : independent of the barrier, issue first ----
        const float* xrow = x + (size_t)t * (B_SZ * I_SZ) + am * I_SZ + kq;
#pragma unroll
        for (int kx = 0; kx < 8; ++kx) {
            f32x4 x0 = *reinterpret_cast<const f32x4*>(xrow + kx * 32);
            f32x4 x1 = *reinterpret_cast<const f32x4*>(xrow + kx * 32 + 4);
            union { u16 u[8]; bf16x8 v; } ax;
#pragma unroll
            for (int j = 0; j < 4; ++j) { ax.u[j] = f2bf(x0[j]); ax.u[4 + j] = f2bf(x1[j]); }
            if ((kx & 3) == 0)      acc0 = __builtin_amdgcn_mfma_f32_16x16x32_bf16(ax.v, wI[kx], acc0, 0, 0, 0);
            else if ((kx & 3) == 1) acc1 = __builtin_amdgcn_mfma_f32_16x16x32_bf16(ax.v, wI[kx], acc1, 0, 0, 0);
            else if ((kx & 3) == 2) acc2 = __builtin_amdgcn_mfma_f32_16x16x32_bf16(ax.v, wI[kx], acc2, 0, 0, 0);
            else                    acc3 = __builtin_amdgcn_mfma_f32_16x16x32_bf16(ax.v, wI[kx], acc3, 0, 0, 0);
        }

        // ---- wait until the whole team published h_t ----
        if (t > 0) {
            if (tid == 0) {
                const unsigned tgt = 32u * (unsigned)t;
                while (__hip_atomic_load(my_ctr, __ATOMIC_RELAXED, __HIP_MEMORY_SCOPE_AGENT) < tgt)
                    __builtin_amdgcn_s_sleep(1);
            }
            __syncthreads();
            __threadfence();   // acquire: invalidate stale cached h lines (cross-XCD safe)
        }

        // ---- h_t @ W_hh^T ----
        const u16* hrow = hcur + am * H_SZ + kq;
#pragma unroll
        for (int kk = 0; kk < 32; ++kk) {
            bf16x8 ah = *reinterpret_cast<const bf16x8*>(hrow + kk * 32);
            if ((kk & 3) == 0)      acc0 = __builtin_amdgcn_mfma_f32_16x16x32_bf16(ah, wB[kk], acc0, 0, 0, 0);
            else if ((kk & 3) == 1) acc1 = __builtin_amdgcn_mfma_f32_16x16x32_bf16(ah, wB[kk], acc1, 0, 0, 0);
            else if ((kk & 3) == 2) acc2 = __builtin_amdgcn_mfma_f32_16x16x32_bf16(ah, wB[kk], acc2, 0, 0, 0);
            else                    acc3 = __builtin_amdgcn_mfma_f32_16x16x32_bf16(ah, wB[kk], acc3, 0, 0, 0);
        }

        // ---- epilogue: bias, tanh, EMA (fp32 master state) ----
        float hn[4];
#pragma unroll
        for (int i = 0; i < 4; ++i) {
            float pre = (acc0[i] + acc1[i]) + (acc2[i] + acc3[i]) + bias_v;
            hn[i] = 0.9f * hown[i] + 0.1f * tanhf(pre);
            hown[i] = hn[i];
        }

        // ---- publish bf16 h_{t+1} to the other buffer ----
#pragma unroll
        for (int i = 0; i < 4; ++i)
            hnxt[(row_base + quad * 4 + i) * H_SZ + gcol] = f2bf(hn[i]);

        __threadfence();   // release: drain + writeback so peers (any XCD) see h
        __syncthreads();   // all 4 waves' stores drained before the signal
        if (tid == 0)
            __hip_atomic_fetch_add(my_ctr, 1u, __ATOMIC_RELEASE, __HIP_MEMORY_SCOPE_AGENT);

        // ---- fp32 outputs (after signal: overlaps peers' barrier wait) ----
        float* orow = out + (size_t)t * (B_SZ * H_SZ);
#pragma unroll
        for (int i = 0; i < 4; ++i)
            orow[(row_base + quad * 4 + i) * H_SZ + gcol] = hn[i];

        if (t == T_STEPS - 1) {
            float* hl = out + (size_t)T_STEPS * (B_SZ * H_SZ);
#pragma unroll
            for (int i = 0; i < 4; ++i)
                hl[(row_base + quad * 4 + i) * H_SZ + gcol] = hn[i];
        }
    }
}

extern "C" void kernel_launch(void* const* d_in, const int* in_sizes, int n_in,
                              void* d_out, int out_size, void* d_ws, size_t ws_size,
                              hipStream_t stream) {
    const float* x    = (const float*)d_in[0];  // [T,B,I]
    const float* h0   = (const float*)d_in[1];  // [1,B,H]
    const float* wih  = (const float*)d_in[2];  // [H,I]
    const float* whh  = (const float*)d_in[3];  // [H,H]
    const float* bias = (const float*)d_in[4];  // [H]
    float* out = (float*)d_out;                 // [T,B,H] ++ [B,H]

    char* ws = (char*)d_ws;
    u16* whh_b = (u16*)(ws);                                  // 2 MB
    u16* wih_b = (u16*)(ws + (size_t)(2u << 20));             // 512 KB
    u16* hp0   = (u16*)(ws + (size_t)(2u << 20) + (1u << 19)); // 512 KB
    u16* hp1   = (u16*)(ws + (size_t)(2u << 20) + (2u << 19)); // 512 KB
    unsigned* ctr = (unsigned*)(ws + (size_t)(2u << 20) + (3u << 19));

    prep_kernel<<<dim3(1024), dim3(256), 0, stream>>>(wih, whh, h0, whh_b, wih_b, hp0, ctr);
    rnn_persistent<<<dim3(256), dim3(256), 0, stream>>>(x, h0, bias, whh_b, wih_b, hp0, hp1, ctr, out);
}